// Round 7
// baseline (1718.799 us; speedup 1.0000x reference)
//
#include <hip/hip_runtime.h>

#define NB 128
#define NS 256
#define NI 64
#define NH 128
#define NL 64
#define NG 384  // 3*NH

typedef _Float16 f16;
typedef __attribute__((ext_vector_type(2))) _Float16 f16x2;

__device__ __forceinline__ float fast_tanh(float x) {
    float e = __expf(2.0f * x);
    return 1.0f - 2.0f / (e + 1.0f);
}
__device__ __forceinline__ float fast_sig(float x) {
    return 1.0f / (1.0f + __expf(-x));
}
// pair reduce via DPP quad_perm [1,0,3,2] (xor 1) — pure VALU
__device__ __forceinline__ float red1(float a) {
    int ai = __builtin_bit_cast(int, a);
    int bi = __builtin_amdgcn_update_dpp(0, ai, 0xB1, 0xF, 0xF, true);
    return a + __builtin_bit_cast(float, bi);
}
__device__ __forceinline__ float fdot2(f16x2 a, f16x2 b, float c) {
#if __has_builtin(__builtin_amdgcn_fdot2)
    return __builtin_amdgcn_fdot2(a, b, c, false);
#else
    return c + (float)a.x * (float)b.x + (float)a.y * (float)b.y;
#endif
}
__device__ __forceinline__ f16x2 bcu(int u) {
    return __builtin_bit_cast(f16x2, u);
}
__device__ __forceinline__ int pack2h(float x, float y) {
    f16x2 v; v.x = (f16)x; v.y = (f16)y;
    return __builtin_bit_cast(int, v);
}
// LDS-only workgroup barrier: does NOT drain vmcnt (global prefetch stays in flight)
__device__ __forceinline__ void sync_lds() {
    asm volatile("s_waitcnt lgkmcnt(0)" ::: "memory");
    __builtin_amdgcn_s_barrier();
    asm volatile("" ::: "memory");
}

// ---- f16 weight tables (pre-rounded once by prep_kernel) ----
__device__ __align__(16) f16 g_W1h[NH * NH];
__device__ __align__(16) f16 g_W2h[NH * NH];
__device__ __align__(16) f16 g_W12h[NH * NH];
__device__ __align__(16) f16 g_Whhh[3 * NH * NH];
__device__ __align__(16) f16 g_Whh2h[3 * NH * NH];
__device__ float g_w1b2[NH];
__device__ float g_whhb2[3 * NH];
// gx fallback buffer (used if d_ws too small): 50.3 MB BSS
__device__ float g_gxfb[(size_t)NS * NB * NG];

// ---------------------------------------------------------------------------
// GX precompute: gx[s][b][j] = b_ih[j] + sum_c x[b][s][c] * W_ih[j][c]
// ---------------------------------------------------------------------------
__global__ __launch_bounds__(384)
void gx_kernel(const float* __restrict__ x, const float* __restrict__ W_ih,
               const float* __restrict__ b_ih, float* __restrict__ gx)
{
    const int s = blockIdx.x;
    const int j = threadIdx.x;
    __shared__ __align__(16) float xs[NB * NI];
    for (int idx = j; idx < NB * NI; idx += 384) {
        int bb = idx >> 6, cc = idx & 63;
        xs[idx] = x[(bb * NS + s) * NI + cc];
    }
    float w[64];
#pragma unroll
    for (int c = 0; c < 64; c += 4)
        *(float4*)&w[c] = *(const float4*)&W_ih[j * NI + c];
    const float bj = b_ih[j];
    __syncthreads();
    for (int bb = 0; bb < NB; bb++) {
        const float* xr = xs + bb * NI;
        float a0 = 0.f, a1 = 0.f, a2 = 0.f, a3 = 0.f;
#pragma unroll
        for (int c = 0; c < 64; c += 4) {
            a0 = fmaf(w[c + 0], xr[c + 0], a0);
            a1 = fmaf(w[c + 1], xr[c + 1], a1);
            a2 = fmaf(w[c + 2], xr[c + 2], a2);
            a3 = fmaf(w[c + 3], xr[c + 3], a3);
        }
        gx[((size_t)s * NB + bb) * NG + j] = ((a0 + a1) + (a2 + a3)) + bj;
    }
}

// ---------------------------------------------------------------------------
// Setup (fp32 math, then round to f16): W12=W1@W2, Whh2=Whh@W2, W1b2, Whhb2,
// plus f16 copies of W1, W2, Whh.
// ---------------------------------------------------------------------------
__global__ __launch_bounds__(128)
void prep_kernel(const float* __restrict__ W1, const float* __restrict__ Whh,
                 const float* __restrict__ W2, const float* __restrict__ b2)
{
    const int i = blockIdx.x;   // 0..511
    const int j = threadIdx.x;  // 0..127
    __shared__ float rowA[NH];
    __shared__ float red[NH];
    const float* src = (i < NH) ? (W1 + i * NH) : (Whh + (size_t)(i - NH) * NH);
    rowA[j] = src[j];
    __syncthreads();
    float acc = 0.f;
    for (int k = 0; k < NH; k++) acc = fmaf(rowA[k], W2[k * NH + j], acc);
    if (i < NH) {
        g_W12h[i * NH + j] = (f16)acc;
        g_W1h[i * NH + j]  = (f16)rowA[j];
        g_W2h[i * NH + j]  = (f16)W2[i * NH + j];
    } else {
        g_Whh2h[(size_t)(i - NH) * NH + j] = (f16)acc;
        g_Whhh[(size_t)(i - NH) * NH + j]  = (f16)rowA[j];
    }
    red[j] = rowA[j] * b2[j];
    __syncthreads();
    for (int off = 64; off > 0; off >>= 1) {
        if (j < off) red[j] += red[j + off];
        __syncthreads();
    }
    if (j == 0) {
        if (i < NH) g_w1b2[i] = red[0];
        else        g_whhb2[i - NH] = red[0];
    }
}

// ---------------------------------------------------------------------------
// Replicated-row matvec via v_readlane broadcast: lane L owns rows 2L,2L+1
// of each weight matrix (64 f16x2 each). Source vector lives as a per-lane
// u32 pack (rows 2L,2L+1). readlane(PK,k) broadcasts cols 2k,2k+1 to all
// lanes as the fdot2 scalar operand. No LDS, no barrier, no cross-lane sum.
// ---------------------------------------------------------------------------
#define RL2(WA, WB, PK, OA, OB)                                                \
    {                                                                          \
        float a0_ = 0.f, a1_ = 0.f, b0_ = 0.f, b1_ = 0.f;                      \
        _Pragma("unroll") for (int k = 0; k < 64; k += 2)                      \
        {                                                                      \
            int s0_ = __builtin_amdgcn_readlane((int)(PK), k);                 \
            int s1_ = __builtin_amdgcn_readlane((int)(PK), k + 1);             \
            a0_ = fdot2(WA[k],     bcu(s0_), a0_);                             \
            b0_ = fdot2(WB[k],     bcu(s0_), b0_);                             \
            a1_ = fdot2(WA[k + 1], bcu(s1_), a1_);                             \
            b1_ = fdot2(WB[k + 1], bcu(s1_), b1_);                             \
        }                                                                      \
        OA = a0_ + a1_;                                                        \
        OB = b0_ + b1_;                                                        \
    }

#define RL4(WA, WB, WC, WD, PK, OA, OB, OC, OD)                                \
    {                                                                          \
        float a0_ = 0.f, a1_ = 0.f, b0_ = 0.f, b1_ = 0.f;                      \
        float c0_ = 0.f, c1_ = 0.f, d0_ = 0.f, d1_ = 0.f;                      \
        _Pragma("unroll") for (int k = 0; k < 64; k += 2)                      \
        {                                                                      \
            int s0_ = __builtin_amdgcn_readlane((int)(PK), k);                 \
            int s1_ = __builtin_amdgcn_readlane((int)(PK), k + 1);             \
            a0_ = fdot2(WA[k],     bcu(s0_), a0_);                             \
            b0_ = fdot2(WB[k],     bcu(s0_), b0_);                             \
            c0_ = fdot2(WC[k],     bcu(s0_), c0_);                             \
            d0_ = fdot2(WD[k],     bcu(s0_), d0_);                             \
            a1_ = fdot2(WA[k + 1], bcu(s1_), a1_);                             \
            b1_ = fdot2(WB[k + 1], bcu(s1_), b1_);                             \
            c1_ = fdot2(WC[k + 1], bcu(s1_), c1_);                             \
            d1_ = fdot2(WD[k + 1], bcu(s1_), d1_);                             \
        }                                                                      \
        OA = a0_ + a1_;                                                        \
        OB = b0_ + b1_;                                                        \
        OC = c0_ + c1_;                                                        \
        OD = d0_ + d1_;                                                        \
    }

// load one full weight row (128 f16) into 64 f16x2 regs, static indices
#define LOADROW(DST, BASE)                                                     \
    {                                                                          \
        _Pragma("unroll") for (int j = 0; j < 16; j++)                         \
        {                                                                      \
            uint4 v_ = *(const uint4*)((const f16*)(BASE) + 8 * j);            \
            DST[4 * j + 0] = bcu(v_.x); DST[4 * j + 1] = bcu(v_.y);            \
            DST[4 * j + 2] = bcu(v_.z); DST[4 * j + 3] = bcu(v_.w);            \
        }                                                                      \
    }

// ---------------------------------------------------------------------------
// Main recurrence: 1 WG / batch element, 256 threads = 4 waves, 1 wave/SIMD.
// Wave 0 = chain (W1,W12,W2 replicated; 8 barrier-free readlane matvecs/step).
// Waves 1-3 = gate waves r/z/n (Whh_g, Whh2_g replicated), 3 barriers/step.
// ---------------------------------------------------------------------------
__global__ __launch_bounds__(256, 1)
void rnn_kernel(const float* __restrict__ times, const float* __restrict__ b_hh,
                const float* __restrict__ b1, const float* __restrict__ b2,
                const float* __restrict__ W_mean, const float* __restrict__ b_mean,
                const float* __restrict__ W_logvar, const float* __restrict__ b_logvar,
                const float* __restrict__ gx,
                float* __restrict__ out)
{
    const int b = blockIdx.x;
    const int t = threadIdx.x;   // 0..255
    const int w = t >> 6;        // wave 0..3
    const int L = t & 63;        // lane

    __shared__ float shT[NS];
    __shared__ int shHA[64];     // hA pack (f16x2 rows 2L,2L+1)
    __shared__ int shS2[64];     // S2 pack
    __shared__ float2 shG[3][64];  // gate preactivations, fp32
    __shared__ __align__(16) float shHf[NH];

    for (int i = t; i < NS; i += 256) shT[i] = times[i];
    __syncthreads();

    if (w == 0) {
        // =================== chain wave ===================
        const int r0 = 2 * L, r1 = 2 * L + 1;
        f16x2 w1a[64], w1b[64];  // W1 rows r0,r1
        f16x2 wca[64], wcb[64];  // W12 rows
        f16x2 w2a[64], w2b[64];  // W2 rows
        LOADROW(w1a, g_W1h + r0 * NH); LOADROW(w1b, g_W1h + r1 * NH);
        LOADROW(wca, g_W12h + r0 * NH); LOADROW(wcb, g_W12h + r1 * NH);
        LOADROW(w2a, g_W2h + r0 * NH); LOADROW(w2b, g_W2h + r1 * NH);
        const float b1r0 = b1[r0], b1r1 = b1[r1];
        const float b2r0 = b2[r0], b2r1 = b2[r1];
        const float wb0 = g_w1b2[r0], wb1 = g_w1b2[r1];

        float h0 = 0.f, h1 = 0.f;
        int hpk = 0;
        // gx prefetch for first step (seq = NS-1)
        const float* gbase = gx + ((size_t)(NS - 1) * NB + b) * NG;
        float2 gr = *(const float2*)(gbase + r0);
        float2 gz = *(const float2*)(gbase + NH + r0);
        float2 gn = *(const float2*)(gbase + 2 * NH + r0);

        for (int si = 0; si < NS; ++si) {
            const int seq = NS - 1 - si;
            const float dt = (si == 0) ? 0.f : (shT[seq] - shT[seq + 1]);
            const float dts = 0.5f * dt;
            const float a2 = 0.5f * dts;
            const float a6 = dts * (1.f / 6.f);

            // prefetch NEXT step's gx (in flight across the whole step)
            const int seqn = (seq > 0) ? (seq - 1) : 0;
            const float* gb = gx + ((size_t)seqn * NB + b) * NG;
            float2 gr_n = *(const float2*)(gb + r0);
            float2 gz_n = *(const float2*)(gb + NH + r0);
            float2 gn_n = *(const float2*)(gb + 2 * NH + r0);

            // st1: z1a = W1 h + b1
            float z0, z1v;
            RL2(w1a, w1b, hpk, z0, z1v);
            z0 += b1r0; z1v += b1r1;
            float u0 = fast_tanh(z0), u1 = fast_tanh(z1v);
            float S0 = u0, S1 = u1;
            int upk = pack2h(u0, u1);
            float m0, m1;
            // st2
            RL2(wca, wcb, upk, m0, m1);
            u0 = fast_tanh(z0 + a2 * (m0 + wb0));
            u1 = fast_tanh(z1v + a2 * (m1 + wb1));
            S0 += 2.f * u0; S1 += 2.f * u1;
            upk = pack2h(u0, u1);
            // st3
            RL2(wca, wcb, upk, m0, m1);
            u0 = fast_tanh(z0 + a2 * (m0 + wb0));
            u1 = fast_tanh(z1v + a2 * (m1 + wb1));
            S0 += 2.f * u0; S1 += 2.f * u1;
            upk = pack2h(u0, u1);
            // st4 (k4 uses full dts)
            RL2(wca, wcb, upk, m0, m1);
            u0 = fast_tanh(z0 + dts * (m0 + wb0));
            u1 = fast_tanh(z1v + dts * (m1 + wb1));
            S0 += u0; S1 += u1;
            int Spk = pack2h(S0, S1);
            // st5 (merged): W12*S (chain) and W2*S (hA) in one loop
            float mA0, mA1, mW0, mW1;
            RL4(wca, wcb, w2a, w2b, Spk, mA0, mA1, mW0, mW1);
            const float zb0 = z0 + a6 * mA0 + dts * wb0;
            const float zb1 = z1v + a6 * mA1 + dts * wb1;
            const float hA0 = h0 + a6 * mW0 + dts * b2r0;
            const float hA1 = h1 + a6 * mW1 + dts * b2r1;
            shHA[L] = pack2h(hA0, hA1);
            u0 = fast_tanh(zb0); u1 = fast_tanh(zb1);
            float S20 = u0, S21 = u1;
            upk = pack2h(u0, u1);
            sync_lds();  // B1: hA published
            // st6
            RL2(wca, wcb, upk, m0, m1);
            u0 = fast_tanh(zb0 + a2 * (m0 + wb0));
            u1 = fast_tanh(zb1 + a2 * (m1 + wb1));
            S20 += 2.f * u0; S21 += 2.f * u1;
            upk = pack2h(u0, u1);
            // st7
            RL2(wca, wcb, upk, m0, m1);
            u0 = fast_tanh(zb0 + a2 * (m0 + wb0));
            u1 = fast_tanh(zb1 + a2 * (m1 + wb1));
            S20 += 2.f * u0; S21 += 2.f * u1;
            upk = pack2h(u0, u1);
            // st8
            RL2(wca, wcb, upk, m0, m1);
            u0 = fast_tanh(zb0 + dts * (m0 + wb0));
            u1 = fast_tanh(zb1 + dts * (m1 + wb1));
            S20 += u0; S21 += u1;
            int S2pk = pack2h(S20, S21);
            shS2[L] = S2pk;
            sync_lds();  // B2: S2 published
            // st9: hB = hA + a6 W2 S2 + dts b2
            float n0, n1;
            RL2(w2a, w2b, S2pk, n0, n1);
            const float hB0 = hA0 + a6 * n0 + dts * b2r0;
            const float hB1 = hA1 + a6 * n1 + dts * b2r1;
            sync_lds();  // B3: gates published G
            float2 Gr = shG[0][L];
            float2 Gz = shG[1][L];
            float2 Gn = shG[2][L];
            const float rr0 = fast_sig(gr.x + Gr.x);
            const float rr1 = fast_sig(gr.y + Gr.y);
            const float zz0 = fast_sig(gz.x + Gz.x);
            const float zz1 = fast_sig(gz.y + Gz.y);
            const float nn0 = fast_tanh(gn.x + rr0 * Gn.x);
            const float nn1 = fast_tanh(gn.y + rr1 * Gn.y);
            h0 = (1.f - zz0) * nn0 + zz0 * hB0;
            h1 = (1.f - zz1) * nn1 + zz1 * hB1;
            hpk = pack2h(h0, h1);
            gr = gr_n; gz = gz_n; gn = gn_n;
        }
        shHf[r0] = h0;
        shHf[r1] = h1;
    } else {
        // =================== gate waves (g = r/z/n) ===================
        const int g = w - 1;
        const int r0 = 2 * L, r1 = 2 * L + 1;
        f16x2 wha[64], whb[64];  // Whh_g rows
        f16x2 wsa[64], wsb[64];  // Whh2_g rows
        LOADROW(wha, g_Whhh + (size_t)(g * NH + r0) * NH);
        LOADROW(whb, g_Whhh + (size_t)(g * NH + r1) * NH);
        LOADROW(wsa, g_Whh2h + (size_t)(g * NH + r0) * NH);
        LOADROW(wsb, g_Whh2h + (size_t)(g * NH + r1) * NH);
        const float bh0 = b_hh[g * NH + r0], bh1 = b_hh[g * NH + r1];
        const float sb0 = g_whhb2[g * NH + r0], sb1 = g_whhb2[g * NH + r1];

        for (int si = 0; si < NS; ++si) {
            const int seq = NS - 1 - si;
            const float dt = (si == 0) ? 0.f : (shT[seq] - shT[seq + 1]);
            const float dts = 0.5f * dt;
            const float a6 = dts * (1.f / 6.f);

            sync_lds();  // B1: hA ready
            int hApk = shHA[L];
            float gA0, gA1;
            RL2(wha, whb, hApk, gA0, gA1);
            sync_lds();  // B2: S2 ready
            int S2pk = shS2[L];
            float gS0, gS1;
            RL2(wsa, wsb, S2pk, gS0, gS1);
            shG[g][L] = make_float2(gA0 + a6 * gS0 + dts * sb0 + bh0,
                                    gA1 + a6 * gS1 + dts * sb1 + bh1);
            sync_lds();  // B3: G published
        }
    }

    // ---- epilogue: heads from final fp32 h ----
    __syncthreads();
    const int rr = t >> 1;
    const int pp = t & 1;
    const int sel = rr >> 6;
    const int l = rr & 63;
    const float* Wf = sel ? W_logvar : W_mean;
    const int hc0 = 64 * pp;
    float a0 = 0.f, a1 = 0.f;
#pragma unroll
    for (int jj = 0; jj < 16; jj++) {
        float4 w4 = *(const float4*)&Wf[l * NH + hc0 + 4 * jj];
        float4 h4 = *(const float4*)(shHf + hc0 + 4 * jj);
        a0 = fmaf(w4.x, h4.x, a0);
        a1 = fmaf(w4.y, h4.y, a1);
        a0 = fmaf(w4.z, h4.z, a0);
        a1 = fmaf(w4.w, h4.w, a1);
    }
    float acc = red1(a0 + a1);
    if (pp == 0) {
        const float bias = sel ? b_logvar[l] : b_mean[l];
        out[sel * (NB * NL) + b * NL + l] = acc + bias;
    }
}

extern "C" void kernel_launch(void* const* d_in, const int* in_sizes, int n_in,
                              void* d_out, int out_size, void* d_ws, size_t ws_size,
                              hipStream_t stream)
{
    const float* x        = (const float*)d_in[0];
    const float* times    = (const float*)d_in[1];
    const float* W_ih     = (const float*)d_in[2];
    const float* W_hh     = (const float*)d_in[3];
    const float* b_ih     = (const float*)d_in[4];
    const float* b_hh     = (const float*)d_in[5];
    const float* W1       = (const float*)d_in[6];
    const float* b1       = (const float*)d_in[7];
    const float* W2       = (const float*)d_in[8];
    const float* b2       = (const float*)d_in[9];
    const float* W_mean   = (const float*)d_in[10];
    const float* b_mean   = (const float*)d_in[11];
    const float* W_logvar = (const float*)d_in[12];
    const float* b_logvar = (const float*)d_in[13];
    float* out = (float*)d_out;

    // gx target: workspace if big enough, else static fallback buffer
    const size_t need = (size_t)NS * NB * NG * sizeof(float);  // ~50.3 MB
    float* gxbuf;
    if (d_ws != nullptr && ws_size >= need) {
        gxbuf = (float*)d_ws;
    } else {
        void* p = nullptr;
        hipGetSymbolAddress(&p, HIP_SYMBOL(g_gxfb));
        gxbuf = (float*)p;
    }

    gx_kernel<<<NS, 384, 0, stream>>>(x, W_ih, b_ih, gxbuf);
    prep_kernel<<<512, 128, 0, stream>>>(W1, W_hh, W2, b2);
    rnn_kernel<<<NB, 256, 0, stream>>>(times, b_hh, b1, b2,
                                       W_mean, b_mean, W_logvar, b_logvar,
                                       gxbuf, out);
}

// Round 8
// 1468.609 us; speedup vs baseline: 1.1704x; 1.1704x over previous
//
#include <hip/hip_runtime.h>

#define NB 128
#define NS 256
#define NI 64
#define NH 128
#define NL 64
#define NG 384  // 3*NH

typedef _Float16 f16;
typedef __attribute__((ext_vector_type(2))) _Float16 f16x2;

__device__ __forceinline__ float fast_tanh(float x) {
    float e = __expf(2.0f * x);
    return 1.0f - 2.0f / (e + 1.0f);
}
__device__ __forceinline__ float fast_sig(float x) {
    return 1.0f / (1.0f + __expf(-x));
}
// pair reduce via DPP quad_perm [1,0,3,2] (epilogue only)
__device__ __forceinline__ float red1(float a) {
    int ai = __builtin_bit_cast(int, a);
    int bi = __builtin_amdgcn_update_dpp(0, ai, 0xB1, 0xF, 0xF, true);
    return a + __builtin_bit_cast(float, bi);
}
__device__ __forceinline__ float fdot2(f16x2 a, f16x2 b, float c) {
#if __has_builtin(__builtin_amdgcn_fdot2)
    return __builtin_amdgcn_fdot2(a, b, c, false);
#else
    return c + (float)a.x * (float)b.x + (float)a.y * (float)b.y;
#endif
}
__device__ __forceinline__ f16x2 bcu(int u) {
    return __builtin_bit_cast(f16x2, u);
}
__device__ __forceinline__ int pack2h(float x, float y) {
    f16x2 v; v.x = (f16)x; v.y = (f16)y;
    return __builtin_bit_cast(int, v);
}
// LDS-only workgroup barrier: does NOT drain vmcnt
__device__ __forceinline__ void sync_lds() {
    asm volatile("s_waitcnt lgkmcnt(0)" ::: "memory");
    __builtin_amdgcn_s_barrier();
    asm volatile("" ::: "memory");
}

// ---- f16 weight tables (pre-rounded once by prep_kernel) ----
__device__ __align__(16) f16 g_W1h[NH * NH];
__device__ __align__(16) f16 g_W2h[NH * NH];
__device__ __align__(16) f16 g_W12h[NH * NH];
__device__ __align__(16) f16 g_Whhh[3 * NH * NH];
__device__ __align__(16) f16 g_Whh2h[3 * NH * NH];
__device__ float g_w1b2[NH];
__device__ float g_whhb2[3 * NH];
// gx fallback buffer (used if d_ws too small)
__device__ float g_gxfb[(size_t)NS * NB * NG];

// ---------------------------------------------------------------------------
// GX precompute: gx[s][b][j] = b_ih[j] + sum_c x[b][s][c] * W_ih[j][c]
// ---------------------------------------------------------------------------
__global__ __launch_bounds__(384)
void gx_kernel(const float* __restrict__ x, const float* __restrict__ W_ih,
               const float* __restrict__ b_ih, float* __restrict__ gx)
{
    const int s = blockIdx.x;
    const int j = threadIdx.x;
    __shared__ __align__(16) float xs[NB * NI];
    for (int idx = j; idx < NB * NI; idx += 384) {
        int bb = idx >> 6, cc = idx & 63;
        xs[idx] = x[(bb * NS + s) * NI + cc];
    }
    float w[64];
#pragma unroll
    for (int c = 0; c < 64; c += 4)
        *(float4*)&w[c] = *(const float4*)&W_ih[j * NI + c];
    const float bj = b_ih[j];
    __syncthreads();
    for (int bb = 0; bb < NB; bb++) {
        const float* xr = xs + bb * NI;
        float a0 = 0.f, a1 = 0.f, a2 = 0.f, a3 = 0.f;
#pragma unroll
        for (int c = 0; c < 64; c += 4) {
            a0 = fmaf(w[c + 0], xr[c + 0], a0);
            a1 = fmaf(w[c + 1], xr[c + 1], a1);
            a2 = fmaf(w[c + 2], xr[c + 2], a2);
            a3 = fmaf(w[c + 3], xr[c + 3], a3);
        }
        gx[((size_t)s * NB + bb) * NG + j] = ((a0 + a1) + (a2 + a3)) + bj;
    }
}

// ---------------------------------------------------------------------------
// Setup (fp32 math, then round to f16)
// ---------------------------------------------------------------------------
__global__ __launch_bounds__(128)
void prep_kernel(const float* __restrict__ W1, const float* __restrict__ Whh,
                 const float* __restrict__ W2, const float* __restrict__ b2)
{
    const int i = blockIdx.x;   // 0..511
    const int j = threadIdx.x;  // 0..127
    __shared__ float rowA[NH];
    __shared__ float red[NH];
    const float* src = (i < NH) ? (W1 + i * NH) : (Whh + (size_t)(i - NH) * NH);
    rowA[j] = src[j];
    __syncthreads();
    float acc = 0.f;
    for (int k = 0; k < NH; k++) acc = fmaf(rowA[k], W2[k * NH + j], acc);
    if (i < NH) {
        g_W12h[i * NH + j] = (f16)acc;
        g_W1h[i * NH + j]  = (f16)rowA[j];
        g_W2h[i * NH + j]  = (f16)W2[i * NH + j];
    } else {
        g_Whh2h[(size_t)(i - NH) * NH + j] = (f16)acc;
        g_Whhh[(size_t)(i - NH) * NH + j]  = (f16)rowA[j];
    }
    red[j] = rowA[j] * b2[j];
    __syncthreads();
    for (int off = 64; off > 0; off >>= 1) {
        if (j < off) red[j] += red[j + off];
        __syncthreads();
    }
    if (j == 0) {
        if (i < NH) g_w1b2[i] = red[0];
        else        g_whhb2[i - NH] = red[0];
    }
}

// ---------------------------------------------------------------------------
// readlane-broadcast matvecs: lane L owns full rows; source vector is a
// per-lane u32 pack (elements 2L,2L+1); readlane(PK,k) broadcasts cols
// 2k,2k+1 to all lanes. No LDS, no barrier, no cross-lane reduction.
// Weight arrays stored as int (u32 = f16x2), literal indices only.
// ---------------------------------------------------------------------------
#define MV2(WA, WB, PK, O0, O1)                                                \
    {                                                                          \
        float a0_ = 0.f, a1_ = 0.f, b0_ = 0.f, b1_ = 0.f;                      \
        _Pragma("unroll") for (int k = 0; k < 32; k++)                         \
        {                                                                      \
            int s0_ = __builtin_amdgcn_readlane((int)(PK), 2 * k);             \
            int s1_ = __builtin_amdgcn_readlane((int)(PK), 2 * k + 1);         \
            a0_ = fdot2(bcu(WA[2 * k]), bcu(s0_), a0_);                        \
            b0_ = fdot2(bcu(WB[2 * k]), bcu(s0_), b0_);                        \
            a1_ = fdot2(bcu(WA[2 * k + 1]), bcu(s1_), a1_);                    \
            b1_ = fdot2(bcu(WB[2 * k + 1]), bcu(s1_), b1_);                    \
        }                                                                      \
        O0 = a0_ + a1_;                                                        \
        O1 = b0_ + b1_;                                                        \
    }

#define MV3(WA, WB, WC, PK, O0, O1, O2)                                        \
    {                                                                          \
        float a0_ = 0.f, a1_ = 0.f, b0_ = 0.f, b1_ = 0.f, c0_ = 0.f, c1_ = 0.f;\
        _Pragma("unroll") for (int k = 0; k < 32; k++)                         \
        {                                                                      \
            int s0_ = __builtin_amdgcn_readlane((int)(PK), 2 * k);             \
            int s1_ = __builtin_amdgcn_readlane((int)(PK), 2 * k + 1);         \
            a0_ = fdot2(bcu(WA[2 * k]), bcu(s0_), a0_);                        \
            b0_ = fdot2(bcu(WB[2 * k]), bcu(s0_), b0_);                        \
            c0_ = fdot2(bcu(WC[2 * k]), bcu(s0_), c0_);                        \
            a1_ = fdot2(bcu(WA[2 * k + 1]), bcu(s1_), a1_);                    \
            b1_ = fdot2(bcu(WB[2 * k + 1]), bcu(s1_), b1_);                    \
            c1_ = fdot2(bcu(WC[2 * k + 1]), bcu(s1_), c1_);                    \
        }                                                                      \
        O0 = a0_ + a1_;                                                        \
        O1 = b0_ + b1_;                                                        \
        O2 = c0_ + c1_;                                                        \
    }

// load one full f16 row (128 = 256B) into int[64]
#define LOADROW(DST, BASE)                                                     \
    {                                                                          \
        const uint4* p_ = (const uint4*)(BASE);                                \
        _Pragma("unroll") for (int j_ = 0; j_ < 16; j_++)                      \
        {                                                                      \
            uint4 v_ = p_[j_];                                                 \
            DST[4 * j_ + 0] = v_.x; DST[4 * j_ + 1] = v_.y;                    \
            DST[4 * j_ + 2] = v_.z; DST[4 * j_ + 3] = v_.w;                    \
        }                                                                      \
    }

// pin an int[64] weight array to arch VGPRs (no-op instructions)
#define PIN2(A, B)                                                             \
    _Pragma("unroll") for (int i_ = 0; i_ < 64; i_++)                          \
    { asm volatile("" : "+v"(A[i_]), "+v"(B[i_])); }
#define PIN3(A, B, C)                                                          \
    _Pragma("unroll") for (int i_ = 0; i_ < 64; i_++)                          \
    { asm volatile("" : "+v"(A[i_]), "+v"(B[i_]), "+v"(C[i_])); }

// ---------------------------------------------------------------------------
// Main recurrence: 1 WG / batch element, 256 threads = 4 waves (1/SIMD).
// Wave 0: z-chain (W12 hot, 7 barrier-free readlane matvecs) + hB tail (W2).
// Wave 1: st1 (W1) + GRU; owns h. Waves 2,3: gates (Whh in window, Whh2 tail).
// 3 barriers/step: B1 (z1a,u1,h) -> B4 (S+S2) -> B5 (G, hB).
// ---------------------------------------------------------------------------
__global__ __launch_bounds__(256, 1)
void rnn_kernel(const float* __restrict__ times, const float* __restrict__ b_hh,
                const float* __restrict__ b1, const float* __restrict__ b2,
                const float* __restrict__ W_mean, const float* __restrict__ b_mean,
                const float* __restrict__ W_logvar, const float* __restrict__ b_logvar,
                const float* __restrict__ gx,
                float* __restrict__ out)
{
    const int b = blockIdx.x;
    const int t = threadIdx.x;   // 0..255
    const int w = t >> 6;        // wave 0..3
    const int L = t & 63;        // lane
    const int r0 = 2 * L, r1 = 2 * L + 1;

    __shared__ float shT[NS];
    __shared__ float2 shZ[64];    // z1a (fp32 pair)
    __shared__ int shU[64];       // u1 pack
    __shared__ int shSpp[64];     // (S + S2) pack
    __shared__ int shHpk[64];     // h pack (f16)
    __shared__ float2 shHf2[64];  // h fp32 pair
    __shared__ float2 shHB[64];   // hB fp32 pair
    __shared__ float shG[NG];     // gate preactivations (flat gate-row)
    __shared__ __align__(16) float shHfl[NH];

    for (int i = t; i < NS; i += 256) shT[i] = times[i];
    if (t < 64) { shHpk[t] = 0; shHf2[t] = make_float2(0.f, 0.f); }
    __syncthreads();

    if (w == 0) {
        // =================== chain wave: W12 hot, W2 cold ===================
        int w12a[64], w12b[64], w2a[64], w2b[64];
        LOADROW(w12a, g_W12h + r0 * NH);
        LOADROW(w12b, g_W12h + r1 * NH);
        LOADROW(w2a, g_W2h + r0 * NH);
        LOADROW(w2b, g_W2h + r1 * NH);
        const float wb0 = g_w1b2[r0], wb1 = g_w1b2[r1];
        const float b20 = b2[r0], b21 = b2[r1];

        for (int si = 0; si < NS; ++si) {
            const int seq = NS - 1 - si;
            const float dt = (si == 0) ? 0.f : (shT[seq] - shT[seq + 1]);
            const float dts = 0.5f * dt;
            const float a2 = 0.5f * dts;
            const float a6 = dts * (1.f / 6.f);
            PIN2(w12a, w12b);
            sync_lds();  // B1: z1a, u1, h published by wave 1
            float2 zf = shZ[L];
            int upk = shU[L];
            const float z0 = zf.x, z1v = zf.y;
            f16x2 uu = bcu(upk);
            float u0 = (float)uu.x, u1 = (float)uu.y;
            float S0 = u0, S1 = u1;
            float m0, m1;
            // st2
            MV2(w12a, w12b, upk, m0, m1);
            u0 = fast_tanh(z0 + a2 * (m0 + wb0));
            u1 = fast_tanh(z1v + a2 * (m1 + wb1));
            S0 += 2.f * u0; S1 += 2.f * u1;
            upk = pack2h(u0, u1);
            // st3
            MV2(w12a, w12b, upk, m0, m1);
            u0 = fast_tanh(z0 + a2 * (m0 + wb0));
            u1 = fast_tanh(z1v + a2 * (m1 + wb1));
            S0 += 2.f * u0; S1 += 2.f * u1;
            upk = pack2h(u0, u1);
            // st4 (k4 uses full dts)
            MV2(w12a, w12b, upk, m0, m1);
            u0 = fast_tanh(z0 + dts * (m0 + wb0));
            u1 = fast_tanh(z1v + dts * (m1 + wb1));
            S0 += u0; S1 += u1;
            // st5: z1b = z1a + a6*(W12 S) + dts*W1b2
            int Spk = pack2h(S0, S1);
            MV2(w12a, w12b, Spk, m0, m1);
            const float zb0 = z0 + a6 * m0 + dts * wb0;
            const float zb1 = z1v + a6 * m1 + dts * wb1;
            u0 = fast_tanh(zb0); u1 = fast_tanh(zb1);
            float S20 = u0, S21 = u1;
            upk = pack2h(u0, u1);
            // st6
            MV2(w12a, w12b, upk, m0, m1);
            u0 = fast_tanh(zb0 + a2 * (m0 + wb0));
            u1 = fast_tanh(zb1 + a2 * (m1 + wb1));
            S20 += 2.f * u0; S21 += 2.f * u1;
            upk = pack2h(u0, u1);
            // st7
            MV2(w12a, w12b, upk, m0, m1);
            u0 = fast_tanh(zb0 + a2 * (m0 + wb0));
            u1 = fast_tanh(zb1 + a2 * (m1 + wb1));
            S20 += 2.f * u0; S21 += 2.f * u1;
            upk = pack2h(u0, u1);
            // st8
            MV2(w12a, w12b, upk, m0, m1);
            u0 = fast_tanh(zb0 + dts * (m0 + wb0));
            u1 = fast_tanh(zb1 + dts * (m1 + wb1));
            S20 += u0; S21 += u1;
            const int SppPk = pack2h(S0 + S20, S1 + S21);
            shSpp[L] = SppPk;
            sync_lds();  // B4: Spp published
            // tail: hB = h + a6*W2*(S+S2) + 2*dts*b2
            float q0, q1;
            MV2(w2a, w2b, SppPk, q0, q1);
            float2 hf = shHf2[L];
            shHB[L] = make_float2(hf.x + a6 * q0 + 2.f * dts * b20,
                                  hf.y + a6 * q1 + 2.f * dts * b21);
            sync_lds();  // B5
        }
    } else if (w == 1) {
        // =================== head wave: W1 + GRU, owns h ===================
        int w1a[64], w1b[64];
        LOADROW(w1a, g_W1h + r0 * NH);
        LOADROW(w1b, g_W1h + r1 * NH);
        const float b10 = b1[r0], b11 = b1[r1];
        float h0 = 0.f, h1 = 0.f;
        int hpk = 0;

        for (int si = 0; si < NS; ++si) {
            const int seq = NS - 1 - si;
            PIN2(w1a, w1b);
            // prefetch gx for this step's GRU (used ~4000 cyc later)
            const float* g = gx + ((size_t)seq * NB + b) * NG;
            float2 gxr = *(const float2*)(g + r0);
            float2 gxz = *(const float2*)(g + NH + r0);
            float2 gxn = *(const float2*)(g + 2 * NH + r0);
            // st1: z1a = W1 h + b1
            float za0, za1;
            MV2(w1a, w1b, hpk, za0, za1);
            za0 += b10; za1 += b11;
            shZ[L] = make_float2(za0, za1);
            shU[L] = pack2h(fast_tanh(za0), fast_tanh(za1));
            sync_lds();  // B1
            sync_lds();  // B4
            sync_lds();  // B5: G + hB ready
            float2 Gr = *(const float2*)&shG[0 * NH + r0];
            float2 Gz = *(const float2*)&shG[1 * NH + r0];
            float2 Gn = *(const float2*)&shG[2 * NH + r0];
            float2 hBf = shHB[L];
            const float rr0 = fast_sig(gxr.x + Gr.x);
            const float rr1 = fast_sig(gxr.y + Gr.y);
            const float zz0 = fast_sig(gxz.x + Gz.x);
            const float zz1 = fast_sig(gxz.y + Gz.y);
            const float nn0 = fast_tanh(gxn.x + rr0 * Gn.x);
            const float nn1 = fast_tanh(gxn.y + rr1 * Gn.y);
            h0 = (1.f - zz0) * nn0 + zz0 * hBf.x;
            h1 = (1.f - zz1) * nn1 + zz1 * hBf.y;
            hpk = pack2h(h0, h1);
            shHpk[L] = hpk;
            shHf2[L] = make_float2(h0, h1);
        }
        shHfl[r0] = h0;
        shHfl[r1] = h1;
    } else {
        // ============ gate waves (w=2,3): 3 gate-rows per lane ============
        const int base = (w - 2) * 192;
        const int gr0 = base + L, gr1 = base + 64 + L, gr2 = base + 128 + L;
        int ha[64], hb[64], hc[64];  // Whh rows (cold: big window)
        int sa[64], sb[64], sc[64];  // Whh2 rows (hot: tail)
        LOADROW(ha, g_Whhh + (size_t)gr0 * NH);
        LOADROW(hb, g_Whhh + (size_t)gr1 * NH);
        LOADROW(hc, g_Whhh + (size_t)gr2 * NH);
        LOADROW(sa, g_Whh2h + (size_t)gr0 * NH);
        LOADROW(sb, g_Whh2h + (size_t)gr1 * NH);
        LOADROW(sc, g_Whh2h + (size_t)gr2 * NH);
        const float bh0 = b_hh[gr0], bh1 = b_hh[gr1], bh2 = b_hh[gr2];
        const float sb0 = g_whhb2[gr0], sb1 = g_whhb2[gr1], sb2 = g_whhb2[gr2];

        for (int si = 0; si < NS; ++si) {
            const int seq = NS - 1 - si;
            const float dt = (si == 0) ? 0.f : (shT[seq] - shT[seq + 1]);
            const float dts = 0.5f * dt;
            const float a6 = dts * (1.f / 6.f);
            PIN3(sa, sb, sc);
            sync_lds();  // B1: h pack ready
            const int hp = shHpk[L];
            float g0, g1, g2;
            MV3(ha, hb, hc, hp, g0, g1, g2);   // Whh·h (huge window)
            sync_lds();  // B4: Spp ready
            const int sp = shSpp[L];
            float s0, s1, s2;
            MV3(sa, sb, sc, sp, s0, s1, s2);   // Whh2·(S+S2) (tail-critical)
            shG[gr0] = g0 + a6 * s0 + 2.f * dts * sb0 + bh0;
            shG[gr1] = g1 + a6 * s1 + 2.f * dts * sb1 + bh1;
            shG[gr2] = g2 + a6 * s2 + 2.f * dts * sb2 + bh2;
            sync_lds();  // B5
        }
    }

    __syncthreads();
    // ---- epilogue: heads from final fp32 h ----
    const int rr = t >> 1;
    const int pp = t & 1;
    const int sel = rr >> 6;
    const int l = rr & 63;
    const float* Wf = sel ? W_logvar : W_mean;
    const int hc0 = 64 * pp;
    float a0 = 0.f, a1 = 0.f;
#pragma unroll
    for (int jj = 0; jj < 16; jj++) {
        float4 w4 = *(const float4*)&Wf[l * NH + hc0 + 4 * jj];
        float4 h4 = *(const float4*)(shHfl + hc0 + 4 * jj);
        a0 = fmaf(w4.x, h4.x, a0);
        a1 = fmaf(w4.y, h4.y, a1);
        a0 = fmaf(w4.z, h4.z, a0);
        a1 = fmaf(w4.w, h4.w, a1);
    }
    float acc = red1(a0 + a1);
    if (pp == 0) {
        const float bias = sel ? b_logvar[l] : b_mean[l];
        out[sel * (NB * NL) + b * NL + l] = acc + bias;
    }
}

extern "C" void kernel_launch(void* const* d_in, const int* in_sizes, int n_in,
                              void* d_out, int out_size, void* d_ws, size_t ws_size,
                              hipStream_t stream)
{
    const float* x        = (const float*)d_in[0];
    const float* times    = (const float*)d_in[1];
    const float* W_ih     = (const float*)d_in[2];
    const float* W_hh     = (const float*)d_in[3];
    const float* b_ih     = (const float*)d_in[4];
    const float* b_hh     = (const float*)d_in[5];
    const float* W1       = (const float*)d_in[6];
    const float* b1       = (const float*)d_in[7];
    const float* W2       = (const float*)d_in[8];
    const float* b2       = (const float*)d_in[9];
    const float* W_mean   = (const float*)d_in[10];
    const float* b_mean   = (const float*)d_in[11];
    const float* W_logvar = (const float*)d_in[12];
    const float* b_logvar = (const float*)d_in[13];
    float* out = (float*)d_out;

    const size_t need = (size_t)NS * NB * NG * sizeof(float);  // ~50.3 MB
    float* gxbuf;
    if (d_ws != nullptr && ws_size >= need) {
        gxbuf = (float*)d_ws;
    } else {
        void* p = nullptr;
        hipGetSymbolAddress(&p, HIP_SYMBOL(g_gxfb));
        gxbuf = (float*)p;
    }

    gx_kernel<<<NS, 384, 0, stream>>>(x, W_ih, b_ih, gxbuf);
    prep_kernel<<<512, 128, 0, stream>>>(W1, W_hh, W2, b2);
    rnn_kernel<<<NB, 256, 0, stream>>>(times, b_hh, b1, b2,
                                       W_mean, b_mean, W_logvar, b_logvar,
                                       gxbuf, out);
}

// Round 9
// 1375.010 us; speedup vs baseline: 1.2500x; 1.0681x over previous
//
#include <hip/hip_runtime.h>

#define NB 128
#define NS 256
#define NI 64
#define NH 128
#define NL 64
#define NG 384  // 3*NH

typedef _Float16 f16;
typedef __attribute__((ext_vector_type(2))) _Float16 f16x2;

__device__ __forceinline__ float fast_tanh(float x) {
    float e = __expf(2.0f * x);
    return 1.0f - 2.0f / (e + 1.0f);
}
__device__ __forceinline__ float fast_sig(float x) {
    return 1.0f / (1.0f + __expf(-x));
}
__device__ __forceinline__ float red1(float a) {  // epilogue pair-reduce
    int ai = __builtin_bit_cast(int, a);
    int bi = __builtin_amdgcn_update_dpp(0, ai, 0xB1, 0xF, 0xF, true);
    return a + __builtin_bit_cast(float, bi);
}
__device__ __forceinline__ float fdot2(f16x2 a, f16x2 b, float c) {
#if __has_builtin(__builtin_amdgcn_fdot2)
    return __builtin_amdgcn_fdot2(a, b, c, false);
#else
    return c + (float)a.x * (float)b.x + (float)a.y * (float)b.y;
#endif
}
__device__ __forceinline__ f16x2 bcu(int u) {
    return __builtin_bit_cast(f16x2, u);
}
__device__ __forceinline__ int pack2h(float x, float y) {
    f16x2 v; v.x = (f16)x; v.y = (f16)y;
    return __builtin_bit_cast(int, v);
}
// LDS-only workgroup barrier (no vmcnt drain: global prefetch stays in flight)
__device__ __forceinline__ void sync_lds() {
    asm volatile("s_waitcnt lgkmcnt(0)" ::: "memory");
    __builtin_amdgcn_s_barrier();
    asm volatile("" ::: "memory");
}

// ---- f16 weight tables (pre-rounded once by prep_kernel) ----
__device__ __align__(16) f16 g_W1h[NH * NH];
__device__ __align__(16) f16 g_W2h[NH * NH];
__device__ __align__(16) f16 g_W12h[NH * NH];
__device__ __align__(16) f16 g_Whhh[3 * NH * NH];
__device__ __align__(16) f16 g_Whh2h[3 * NH * NH];
__device__ float g_w1b2[NH];
__device__ float g_whhb2[3 * NH];
__device__ float g_gxfb[(size_t)NS * NB * NG];  // gx fallback if ws too small

// ---------------------------------------------------------------------------
// GX precompute: gx[s][b][j] = b_ih[j] + sum_c x[b][s][c] * W_ih[j][c]
// ---------------------------------------------------------------------------
__global__ __launch_bounds__(384)
void gx_kernel(const float* __restrict__ x, const float* __restrict__ W_ih,
               const float* __restrict__ b_ih, float* __restrict__ gx)
{
    const int s = blockIdx.x;
    const int j = threadIdx.x;
    __shared__ __align__(16) float xs[NB * NI];
    for (int idx = j; idx < NB * NI; idx += 384) {
        int bb = idx >> 6, cc = idx & 63;
        xs[idx] = x[(bb * NS + s) * NI + cc];
    }
    float w[64];
#pragma unroll
    for (int c = 0; c < 64; c += 4)
        *(float4*)&w[c] = *(const float4*)&W_ih[j * NI + c];
    const float bj = b_ih[j];
    __syncthreads();
    for (int bb = 0; bb < NB; bb++) {
        const float* xr = xs + bb * NI;
        float a0 = 0.f, a1 = 0.f, a2 = 0.f, a3 = 0.f;
#pragma unroll
        for (int c = 0; c < 64; c += 4) {
            a0 = fmaf(w[c + 0], xr[c + 0], a0);
            a1 = fmaf(w[c + 1], xr[c + 1], a1);
            a2 = fmaf(w[c + 2], xr[c + 2], a2);
            a3 = fmaf(w[c + 3], xr[c + 3], a3);
        }
        gx[((size_t)s * NB + bb) * NG + j] = ((a0 + a1) + (a2 + a3)) + bj;
    }
}

// ---------------------------------------------------------------------------
// Setup (fp32 math, then round to f16): W12=W1@W2, Whh2=Whh@W2, W1b2, Whhb2,
// plus f16 copies of W1, W2, Whh.
// ---------------------------------------------------------------------------
__global__ __launch_bounds__(128)
void prep_kernel(const float* __restrict__ W1, const float* __restrict__ Whh,
                 const float* __restrict__ W2, const float* __restrict__ b2)
{
    const int i = blockIdx.x;   // 0..511
    const int j = threadIdx.x;  // 0..127
    __shared__ float rowA[NH];
    __shared__ float red[NH];
    const float* src = (i < NH) ? (W1 + i * NH) : (Whh + (size_t)(i - NH) * NH);
    rowA[j] = src[j];
    __syncthreads();
    float acc = 0.f;
    for (int k = 0; k < NH; k++) acc = fmaf(rowA[k], W2[k * NH + j], acc);
    if (i < NH) {
        g_W12h[i * NH + j] = (f16)acc;
        g_W1h[i * NH + j]  = (f16)rowA[j];
        g_W2h[i * NH + j]  = (f16)W2[i * NH + j];
    } else {
        g_Whh2h[(size_t)(i - NH) * NH + j] = (f16)acc;
        g_Whhh[(size_t)(i - NH) * NH + j]  = (f16)rowA[j];
    }
    red[j] = rowA[j] * b2[j];
    __syncthreads();
    for (int off = 64; off > 0; off >>= 1) {
        if (j < off) red[j] += red[j + off];
        __syncthreads();
    }
    if (j == 0) {
        if (i < NH) g_w1b2[i] = red[0];
        else        g_whhb2[i - NH] = red[0];
    }
}

// ---------------------------------------------------------------------------
// bpermute-broadcast matvec: PK = per-lane u32 pack (elements 2L,2L+1).
// ds_bpermute(4k, PK) broadcasts lane k's pack to all lanes (register
// crossbar — no LDS memory, no barrier, lgkmcnt-pipelined).
// Weights: int[64] per row, literal indices only.
// ---------------------------------------------------------------------------
#define BDOT(WA, WB, PK, O0, O1)                                               \
    {                                                                          \
        float a0_ = 0.f, a1_ = 0.f, b0_ = 0.f, b1_ = 0.f;                      \
        _Pragma("unroll") for (int k = 0; k < 64; k += 2)                      \
        {                                                                      \
            int v0_ = __builtin_amdgcn_ds_bpermute(4 * k, (PK));               \
            int v1_ = __builtin_amdgcn_ds_bpermute(4 * k + 4, (PK));           \
            a0_ = fdot2(bcu(WA[k]), bcu(v0_), a0_);                            \
            b0_ = fdot2(bcu(WB[k]), bcu(v0_), b0_);                            \
            a1_ = fdot2(bcu(WA[k + 1]), bcu(v1_), a1_);                        \
            b1_ = fdot2(bcu(WB[k + 1]), bcu(v1_), b1_);                        \
        }                                                                      \
        O0 = a0_ + a1_;                                                        \
        O1 = b0_ + b1_;                                                        \
    }

// load one full f16 row (128 = 256B) into int[64]
#define LOADROW(DST, BASE)                                                     \
    {                                                                          \
        const uint4* p_ = (const uint4*)(BASE);                                \
        _Pragma("unroll") for (int j_ = 0; j_ < 16; j_++)                      \
        {                                                                      \
            uint4 v_ = p_[j_];                                                 \
            DST[4 * j_ + 0] = v_.x; DST[4 * j_ + 1] = v_.y;                    \
            DST[4 * j_ + 2] = v_.z; DST[4 * j_ + 3] = v_.w;                    \
        }                                                                      \
    }

#define PIN2(A, B)                                                             \
    _Pragma("unroll") for (int i_ = 0; i_ < 64; i_++)                          \
    { asm volatile("" : "+v"(A[i_]), "+v"(B[i_])); }

// ---------------------------------------------------------------------------
// Main recurrence: 1 WG / batch element, 512 threads = 8 waves (2/SIMD).
// w0: st1 (W1 from swizzled LDS) + barrier-free bpermute chain (W12 regs).
// w1: W2 -> hB; owns h; GRU. w2-4: Whh_g·h (chain window). w5-7: Whh2_g·Spp.
// 3 barriers/step: B_h -> B2 (Spp+GA) -> B_fin (GS).
// ---------------------------------------------------------------------------
__global__ __launch_bounds__(512, 2)
void rnn_kernel(const float* __restrict__ times, const float* __restrict__ b_hh,
                const float* __restrict__ b1, const float* __restrict__ b2,
                const float* __restrict__ W_mean, const float* __restrict__ b_mean,
                const float* __restrict__ W_logvar, const float* __restrict__ b_logvar,
                const float* __restrict__ gx,
                float* __restrict__ out)
{
    const int b = blockIdx.x;
    const int t = threadIdx.x;   // 0..511
    const int w = t >> 6;        // wave 0..7
    const int L = t & 63;        // lane
    const int r0 = 2 * L, r1 = 2 * L + 1;
    const int key = L & 7;       // sW1 swizzle key (= (r0>>1)&7 = (r1>>1)&7)

    __shared__ float shT[NS];
    __shared__ int shHpk[64];        // h pack (f16x2 rows 2L,2L+1)
    __shared__ int shSpp[64];        // (S+S2) pack
    __shared__ float2 shGA[3][64];   // Whh_g · h
    __shared__ float2 shGS[3][64];   // Whh2_g · Spp
    __shared__ __align__(16) unsigned int sW1[NH * 64];  // 32KB swizzled W1
    __shared__ __align__(16) float shHfl[NH];

    // stage sW1 (chunk j of row r stored at j ^ ((r>>1)&7)) — conflict-free reads
    for (int idx = t; idx < NH * 16; idx += 512) {
        const int r = idx >> 4, j = idx & 15;
        uint4 v = ((const uint4*)g_W1h)[idx];
        ((uint4*)sW1)[(r << 4) | (j ^ ((r >> 1) & 7))] = v;
    }
    for (int i = t; i < NS; i += 512) shT[i] = times[i];
    if (t < 64) shHpk[t] = 0;
    __syncthreads();

    // ---- per-wave persistent weight rows (<=128 u32) ----
    int wa[64], wb[64];
    if (w == 0) {
        LOADROW(wa, g_W12h + r0 * NH);
        LOADROW(wb, g_W12h + r1 * NH);
    } else if (w == 1) {
        LOADROW(wa, g_W2h + r0 * NH);
        LOADROW(wb, g_W2h + r1 * NH);
    } else if (w <= 4) {
        const int g = w - 2;
        LOADROW(wa, g_Whhh + (size_t)(g * NH + r0) * NH);
        LOADROW(wb, g_Whhh + (size_t)(g * NH + r1) * NH);
    } else {
        const int g = w - 5;
        LOADROW(wa, g_Whh2h + (size_t)(g * NH + r0) * NH);
        LOADROW(wb, g_Whh2h + (size_t)(g * NH + r1) * NH);
    }

    const float b1r0 = b1[r0], b1r1 = b1[r1];
    const float w1b20 = g_w1b2[r0], w1b21 = g_w1b2[r1];
    const float b20 = b2[r0], b21 = b2[r1];
    // w1 GRU scalars
    float bhr0 = 0, bhr1 = 0, bhz0 = 0, bhz1 = 0, bhn0 = 0, bhn1 = 0;
    float sbr0 = 0, sbr1 = 0, sbz0 = 0, sbz1 = 0, sbn0 = 0, sbn1 = 0;
    if (w == 1) {
        bhr0 = b_hh[r0]; bhr1 = b_hh[r1];
        bhz0 = b_hh[NH + r0]; bhz1 = b_hh[NH + r1];
        bhn0 = b_hh[2 * NH + r0]; bhn1 = b_hh[2 * NH + r1];
        sbr0 = g_whhb2[r0]; sbr1 = g_whhb2[r1];
        sbz0 = g_whhb2[NH + r0]; sbz1 = g_whhb2[NH + r1];
        sbn0 = g_whhb2[2 * NH + r0]; sbn1 = g_whhb2[2 * NH + r1];
    }

    float h0 = 0.f, h1 = 0.f;               // live in w1
    float2 gxr, gxz, gxn;                   // w1 gx prefetch

    for (int si = 0; si < NS; ++si) {
        const int seq = NS - 1 - si;
        const float dt = (si == 0) ? 0.f : (shT[seq] - shT[seq + 1]);
        const float dts = 0.5f * dt;   // substep dt (N_SUB=2)
        const float a2c = 0.5f * dts;
        const float a6 = dts * (1.f / 6.f);

        sync_lds();  // ===== B_h: h pack from previous iteration visible =====

        if (w == 0) {
            PIN2(wa, wb);
            const int hpk = shHpk[L];
            // ---- st1: z1a = W1 h + b1 (W1 streamed from swizzled LDS) ----
            float z1a0, z1a1;
            {
                float a0_ = 0.f, a1_ = 0.f, c0_ = 0.f, c1_ = 0.f;
#pragma unroll
                for (int c = 0; c < 8; c++) {
                    uint4 va  = ((const uint4*)sW1)[(r0 << 4) | ((2 * c) ^ key)];
                    uint4 va2 = ((const uint4*)sW1)[(r0 << 4) | ((2 * c + 1) ^ key)];
                    uint4 vb  = ((const uint4*)sW1)[(r1 << 4) | ((2 * c) ^ key)];
                    uint4 vb2 = ((const uint4*)sW1)[(r1 << 4) | ((2 * c + 1) ^ key)];
                    int p0 = __builtin_amdgcn_ds_bpermute(4 * (8 * c + 0), hpk);
                    int p1 = __builtin_amdgcn_ds_bpermute(4 * (8 * c + 1), hpk);
                    int p2 = __builtin_amdgcn_ds_bpermute(4 * (8 * c + 2), hpk);
                    int p3 = __builtin_amdgcn_ds_bpermute(4 * (8 * c + 3), hpk);
                    int p4 = __builtin_amdgcn_ds_bpermute(4 * (8 * c + 4), hpk);
                    int p5 = __builtin_amdgcn_ds_bpermute(4 * (8 * c + 5), hpk);
                    int p6 = __builtin_amdgcn_ds_bpermute(4 * (8 * c + 6), hpk);
                    int p7 = __builtin_amdgcn_ds_bpermute(4 * (8 * c + 7), hpk);
                    a0_ = fdot2(bcu(va.x),  bcu(p0), a0_);
                    a1_ = fdot2(bcu(va.y),  bcu(p1), a1_);
                    a0_ = fdot2(bcu(va.z),  bcu(p2), a0_);
                    a1_ = fdot2(bcu(va.w),  bcu(p3), a1_);
                    a0_ = fdot2(bcu(va2.x), bcu(p4), a0_);
                    a1_ = fdot2(bcu(va2.y), bcu(p5), a1_);
                    a0_ = fdot2(bcu(va2.z), bcu(p6), a0_);
                    a1_ = fdot2(bcu(va2.w), bcu(p7), a1_);
                    c0_ = fdot2(bcu(vb.x),  bcu(p0), c0_);
                    c1_ = fdot2(bcu(vb.y),  bcu(p1), c1_);
                    c0_ = fdot2(bcu(vb.z),  bcu(p2), c0_);
                    c1_ = fdot2(bcu(vb.w),  bcu(p3), c1_);
                    c0_ = fdot2(bcu(vb2.x), bcu(p4), c0_);
                    c1_ = fdot2(bcu(vb2.y), bcu(p5), c1_);
                    c0_ = fdot2(bcu(vb2.z), bcu(p6), c0_);
                    c1_ = fdot2(bcu(vb2.w), bcu(p7), c1_);
                }
                z1a0 = a0_ + a1_ + b1r0;
                z1a1 = c0_ + c1_ + b1r1;
            }
            // ---- barrier-free chain st2..st8 ----
            float u0 = fast_tanh(z1a0), u1 = fast_tanh(z1a1);
            float S0 = u0, S1 = u1;
            int upk = pack2h(u0, u1);
            float m0, m1;
            // st2
            BDOT(wa, wb, upk, m0, m1);
            u0 = fast_tanh(z1a0 + a2c * (m0 + w1b20));
            u1 = fast_tanh(z1a1 + a2c * (m1 + w1b21));
            S0 += 2.f * u0; S1 += 2.f * u1;
            upk = pack2h(u0, u1);
            // st3
            BDOT(wa, wb, upk, m0, m1);
            u0 = fast_tanh(z1a0 + a2c * (m0 + w1b20));
            u1 = fast_tanh(z1a1 + a2c * (m1 + w1b21));
            S0 += 2.f * u0; S1 += 2.f * u1;
            upk = pack2h(u0, u1);
            // st4 (k4 uses full dts)
            BDOT(wa, wb, upk, m0, m1);
            u0 = fast_tanh(z1a0 + dts * (m0 + w1b20));
            u1 = fast_tanh(z1a1 + dts * (m1 + w1b21));
            S0 += u0; S1 += u1;
            // st5: z1b = z1a + a6*W12*S + dts*w1b2
            int Spk = pack2h(S0, S1);
            BDOT(wa, wb, Spk, m0, m1);
            const float zb0 = z1a0 + a6 * m0 + dts * w1b20;
            const float zb1 = z1a1 + a6 * m1 + dts * w1b21;
            u0 = fast_tanh(zb0); u1 = fast_tanh(zb1);
            float S20 = u0, S21 = u1;
            upk = pack2h(u0, u1);
            // st6
            BDOT(wa, wb, upk, m0, m1);
            u0 = fast_tanh(zb0 + a2c * (m0 + w1b20));
            u1 = fast_tanh(zb1 + a2c * (m1 + w1b21));
            S20 += 2.f * u0; S21 += 2.f * u1;
            upk = pack2h(u0, u1);
            // st7
            BDOT(wa, wb, upk, m0, m1);
            u0 = fast_tanh(zb0 + a2c * (m0 + w1b20));
            u1 = fast_tanh(zb1 + a2c * (m1 + w1b21));
            S20 += 2.f * u0; S21 += 2.f * u1;
            upk = pack2h(u0, u1);
            // st8
            BDOT(wa, wb, upk, m0, m1);
            u0 = fast_tanh(zb0 + dts * (m0 + w1b20));
            u1 = fast_tanh(zb1 + dts * (m1 + w1b21));
            S20 += u0; S21 += u1;
            shSpp[L] = pack2h(S0 + S20, S1 + S21);
        } else if (w >= 2 && w <= 4) {
            // gates part 1: Whh_g · h (huge window, off critical path)
            const int hpk = shHpk[L];
            float g0, g1;
            BDOT(wa, wb, hpk, g0, g1);
            shGA[w - 2][L] = make_float2(g0, g1);
        } else if (w == 1) {
            // issue gx loads (consumed after B_fin; vmcnt not drained by sync_lds)
            const float* gp = gx + ((size_t)seq * NB + b) * NG;
            gxr = *(const float2*)(gp + r0);
            gxz = *(const float2*)(gp + NH + r0);
            gxn = *(const float2*)(gp + 2 * NH + r0);
        }

        sync_lds();  // ===== B2: Spp + GA visible =====

        float hB0 = 0.f, hB1 = 0.f;
        if (w == 1) {
            const int spk = shSpp[L];
            float q0, q1;
            BDOT(wa, wb, spk, q0, q1);
            hB0 = h0 + a6 * q0 + 2.f * dts * b20;
            hB1 = h1 + a6 * q1 + 2.f * dts * b21;
        } else if (w >= 5) {
            const int spk = shSpp[L];
            float s0, s1;
            BDOT(wa, wb, spk, s0, s1);
            shGS[w - 5][L] = make_float2(s0, s1);
        }

        sync_lds();  // ===== B_fin: GS visible =====

        if (w == 1) {
            const float tdts = 2.f * dts;
            float2 GAr = shGA[0][L], GAz = shGA[1][L], GAn = shGA[2][L];
            float2 GSr = shGS[0][L], GSz = shGS[1][L], GSn = shGS[2][L];
            const float ghr0 = GAr.x + a6 * GSr.x + tdts * sbr0 + bhr0;
            const float ghr1 = GAr.y + a6 * GSr.y + tdts * sbr1 + bhr1;
            const float ghz0 = GAz.x + a6 * GSz.x + tdts * sbz0 + bhz0;
            const float ghz1 = GAz.y + a6 * GSz.y + tdts * sbz1 + bhz1;
            const float ghn0 = GAn.x + a6 * GSn.x + tdts * sbn0 + bhn0;
            const float ghn1 = GAn.y + a6 * GSn.y + tdts * sbn1 + bhn1;
            const float rr0 = fast_sig(gxr.x + ghr0);
            const float rr1 = fast_sig(gxr.y + ghr1);
            const float zz0 = fast_sig(gxz.x + ghz0);
            const float zz1 = fast_sig(gxz.y + ghz1);
            const float nn0 = fast_tanh(gxn.x + rr0 * ghn0);
            const float nn1 = fast_tanh(gxn.y + rr1 * ghn1);
            h0 = (1.f - zz0) * nn0 + zz0 * hB0;
            h1 = (1.f - zz1) * nn1 + zz1 * hB1;
            shHpk[L] = pack2h(h0, h1);   // visible at next iteration's B_h
        }
    }

    // ---- epilogue: heads from final fp32 h ----
    if (w == 1) { shHfl[r0] = h0; shHfl[r1] = h1; }
    __syncthreads();
    if (t < 256) {
        const int rr = t >> 1;
        const int pp = t & 1;
        const int sel = rr >> 6;
        const int l = rr & 63;
        const float* Wf = sel ? W_logvar : W_mean;
        const int hc0 = 64 * pp;
        float a0 = 0.f, a1 = 0.f;
#pragma unroll
        for (int jj = 0; jj < 16; jj++) {
            float4 w4 = *(const float4*)&Wf[l * NH + hc0 + 4 * jj];
            float4 h4 = *(const float4*)(shHfl + hc0 + 4 * jj);
            a0 = fmaf(w4.x, h4.x, a0);
            a1 = fmaf(w4.y, h4.y, a1);
            a0 = fmaf(w4.z, h4.z, a0);
            a1 = fmaf(w4.w, h4.w, a1);
        }
        float acc = red1(a0 + a1);
        if (pp == 0) {
            const float bias = sel ? b_logvar[l] : b_mean[l];
            out[sel * (NB * NL) + b * NL + l] = acc + bias;
        }
    }
}

extern "C" void kernel_launch(void* const* d_in, const int* in_sizes, int n_in,
                              void* d_out, int out_size, void* d_ws, size_t ws_size,
                              hipStream_t stream)
{
    const float* x        = (const float*)d_in[0];
    const float* times    = (const float*)d_in[1];
    const float* W_ih     = (const float*)d_in[2];
    const float* W_hh     = (const float*)d_in[3];
    const float* b_ih     = (const float*)d_in[4];
    const float* b_hh     = (const float*)d_in[5];
    const float* W1       = (const float*)d_in[6];
    const float* b1       = (const float*)d_in[7];
    const float* W2       = (const float*)d_in[8];
    const float* b2       = (const float*)d_in[9];
    const float* W_mean   = (const float*)d_in[10];
    const float* b_mean   = (const float*)d_in[11];
    const float* W_logvar = (const float*)d_in[12];
    const float* b_logvar = (const float*)d_in[13];
    float* out = (float*)d_out;

    const size_t need = (size_t)NS * NB * NG * sizeof(float);  // ~50.3 MB
    float* gxbuf;
    if (d_ws != nullptr && ws_size >= need) {
        gxbuf = (float*)d_ws;
    } else {
        void* p = nullptr;
        hipGetSymbolAddress(&p, HIP_SYMBOL(g_gxfb));
        gxbuf = (float*)p;
    }

    gx_kernel<<<NS, 384, 0, stream>>>(x, W_ih, b_ih, gxbuf);
    prep_kernel<<<512, 128, 0, stream>>>(W1, W_hh, W2, b2);
    rnn_kernel<<<NB, 512, 0, stream>>>(times, b_hh, b1, b2,
                                       W_mean, b_mean, W_logvar, b_logvar,
                                       gxbuf, out);
}